// Round 19
// baseline (279.098 us; speedup 1.0000x reference)
//
#include <hip/hip_runtime.h>
#include <cstdint>
#include <cstddef>

typedef __attribute__((ext_vector_type(8))) short bf16x8;
typedef __attribute__((ext_vector_type(16))) float f32x16;
typedef __attribute__((ext_vector_type(4))) unsigned int u32x4;
typedef unsigned short u16;

#define H1_ROW_B   1920                 /* packed row: 30x * 32ci * 2B     */
#define H1_BATCH   (30 * 30 * 960)      /* elems per batch (864000)        */
#define LDS_STRIDE 1952                 /* 1920 + 32 pad                   */
#define OUT_CSTR   21952                /* 28*28*28                        */

__device__ __forceinline__ u16 f2bf(float f) {
    union { float f; unsigned u; } v; v.f = f;
    unsigned r = v.u + 0x7FFF + ((v.u >> 16) & 1);   // RNE
    return (u16)(r >> 16);
}

__device__ __forceinline__ void fma4(float4& a, float s, const float4& w) {
    a.x = fmaf(s, w.x, a.x);
    a.y = fmaf(s, w.y, a.y);
    a.z = fmaf(s, w.z, a.z);
    a.w = fmaf(s, w.w, a.w);
}

__device__ __forceinline__ void gld_lds(const char* src, unsigned char* dst) {
    __builtin_amdgcn_global_load_lds(
        (const __attribute__((address_space(1))) void*)src,
        (__attribute__((address_space(3))) void*)dst, 16, 0, 0);
}

// ---------------- conv1 + bias + relu -> bf16 h1 (SWIZZLED) ---------------
// h1 in-row layout: byte offset (x*64 + ci*2) with 16B-granule XOR-swizzle
// byte ^= ((x>>1)&3)<<4 — makes conv2's 32x32 A-frag ds_read_b128 pattern
// bank-uniform (linear staging copy preserves it; read applies same XOR).
__global__ __launch_bounds__(256) void conv1_relu(
    const float* __restrict__ x, const float* __restrict__ w1,
    const float* __restrict__ b1, u16* __restrict__ h1, int b0)
{
    __shared__ float xs[3 * 8 * 32];     // [zp][y][x] f32, 3 KB

    const int z   = blockIdx.x;        // 0..29
    const int yt  = blockIdx.y;        // 0..4
    const int bl  = blockIdx.z;
    const int b   = b0 + bl;
    const int tid = threadIdx.x;
    const int y0  = yt * 6;

    if (tid < 192) {
        const int idx = tid * 4;
        const int zp  = idx >> 8;
        const int rem = idx & 255;
        const int yy  = rem >> 5;
        const int xx  = rem & 31;
        const float4 v = *reinterpret_cast<const float4*>(
            x + (size_t)b * 32768 + ((size_t)(z + zp) * 32 + (y0 + yy)) * 32 + xx);
        *reinterpret_cast<float4*>(&xs[idx]) = v;
    }

    const int c4   = tid & 7;
    const int slot = tid >> 3;

    float4 wr[27];
#pragma unroll
    for (int t = 0; t < 27; ++t)
        wr[t] = *reinterpret_cast<const float4*>(w1 + t * 32 + c4 * 4);
    const float4 bias = *reinterpret_cast<const float4*>(b1 + c4 * 4);

    __syncthreads();

    u16* h1b = h1 + (size_t)bl * H1_BATCH;

    if (slot < 30) {
#pragma unroll
        for (int j = 0; j < 3; ++j) {
            const int p  = slot + 30 * j;
            const int yy = p / 15;
            const int xp = p - yy * 15;       // x-pair index; x = 2*xp
            const int xx = xp * 2;
            const int y  = y0 + yy;

            float4 acc0 = bias, acc1 = bias;
#pragma unroll
            for (int kd = 0; kd < 3; ++kd) {
#pragma unroll
                for (int kh = 0; kh < 3; ++kh) {
                    const float* row = &xs[((kd * 8) + (yy + kh)) * 32 + xx];
                    const float2 v01 = *reinterpret_cast<const float2*>(row);
                    const float2 v23 = *reinterpret_cast<const float2*>(row + 2);
                    const int t = (kd * 3 + kh) * 3;
                    fma4(acc0, v01.x, wr[t + 0]);
                    fma4(acc0, v01.y, wr[t + 1]);
                    fma4(acc0, v23.x, wr[t + 2]);
                    fma4(acc1, v01.y, wr[t + 0]);
                    fma4(acc1, v23.x, wr[t + 1]);
                    fma4(acc1, v23.y, wr[t + 2]);
                }
            }
            ushort4 s0, s1;
            s0.x = f2bf(fmaxf(acc0.x, 0.f)); s0.y = f2bf(fmaxf(acc0.y, 0.f));
            s0.z = f2bf(fmaxf(acc0.z, 0.f)); s0.w = f2bf(fmaxf(acc0.w, 0.f));
            s1.x = f2bf(fmaxf(acc1.x, 0.f)); s1.y = f2bf(fmaxf(acc1.y, 0.f));
            s1.z = f2bf(fmaxf(acc1.z, 0.f)); s1.w = f2bf(fmaxf(acc1.w, 0.f));
            // swizzled write: u16 off = x*32 + ((c4*4) ^ (s2<<3)), s2=(x>>1)&3
            const int s2 = xp & 3;
            u16* dst = h1b + ((size_t)(z * 30 + y) * 30 + xx) * 32
                           + ((c4 * 4) ^ (s2 << 3));
            *reinterpret_cast<ushort4*>(dst)      = s0;
            *reinterpret_cast<ushort4*>(dst + 32) = s1;
        }
    }
}

// ---------------- pack w2 -> 32x32x16 B-fragments -------------------------
// frag f = ks*2 + nf at wB + ((tap*4+f)*64 + l)*8:
//   [j] = bf16(w2[tap][ci = ks*16 + (l>>5)*8 + j][co = nf*32 + (l&31)])
__global__ __launch_bounds__(256) void pack_w2(
    const float* __restrict__ w2, u16* __restrict__ wB)
{
    const int tap = blockIdx.x;      // 0..26
    const int tid = threadIdx.x;
    const int f  = tid >> 6;         // 0..3 = ks*2+nf
    const int l  = tid & 63;
    const int ks = f >> 1, nf = f & 1;
    const int co = nf * 32 + (l & 31);
    u16* dst = wB + ((size_t)(tap * 4 + f) * 64 + l) * 8;
#pragma unroll
    for (int j = 0; j < 8; ++j) {
        const int ci = ks * 16 + (l >> 5) * 8 + j;
        dst[j] = f2bf(w2[(size_t)(tap * 32 + ci) * 64 + co]);
    }
}

// ---------------- conv2: 32x32x16 MFMA, 8-wave ----------------------------
// Grid 49*bc x 512 thr (XCD-swizzled). Block tile: 4z x 4y x 28x.
// Wave wv = (zw=wv>>1, mh=wv&1): z-plane z0+zw, y-half mh (2y x 28x = 56
// sites), FULL N=64. Two 32-row m-tiles at x0 = {0,12} (4-col overlap ->
// duplicate identical stores, no masking, no OOB: max x_in = 29).
// A-frag: m-row = lane&31 -> site (yy=(l&31)>>4, x=x0+(l&15)); k=(l>>5)*8+j.
// LDS reads conflict-free via the conv1-side XOR swizzle.
// Per wave-tap: 4 ds_read_b128 + 8 MFMA (vs 7 + 14 before) — denser issue
// stream on the 15%-faster 32x32 shape. B 4KB/wave/tap, 1-ahead vmcnt(4).
__global__ __launch_bounds__(512, 4) void conv2_mfma(
    const u16* __restrict__ h1, const u16* __restrict__ wB,
    const float* __restrict__ b2, float* __restrict__ out, int b0)
{
    __shared__ __align__(16) unsigned char smem[36 * LDS_STRIDE];  // 70272 B

    const int g   = gridDim.x;
    const int bid = blockIdx.x;
    const int lb  = (g % 8 == 0) ? ((bid & 7) * (g >> 3) + (bid >> 3)) : bid;

    const int t0  = lb % 49;
    const int bl  = lb / 49;
    const int yg  = t0 % 7;
    const int zt  = t0 / 7;

    const int b  = b0 + bl;
    const int y0 = yg * 4, z0 = zt * 4;
    const int tid = threadIdx.x;
    const int wv  = tid >> 6;       // 0..7
    const int l   = tid & 63;
    const int zw  = wv >> 1;        // z-plane 0..3
    const int mh  = wv & 1;         // y-half
    const int c   = l & 31;         // co-lane / A m-row
    const int kh  = l >> 5;         // k-half
    const int xi  = l & 15;
    const int yl  = (l >> 4) & 1;

    const char* wBl = (const char*)wB + (size_t)l * 16;

    // ---- stage A: 36 rows x 1920 B, chunks at 0 and 896 (128 B overlap) --
    {
        const char* gbase = (const char*)(h1 + (size_t)bl * H1_BATCH);
        for (int cc = wv; cc < 72; cc += 8) {
            const int rid = cc >> 1, half = cc & 1;
            const int zz = rid / 6, yy = rid - zz * 6;
            const char* src = gbase
                + (size_t)((z0 + zz) * 30 + (y0 + yy)) * H1_ROW_B
                + half * 896 + l * 16;
            unsigned char* dst = smem + rid * LDS_STRIDE + half * 896 + l * 16;
            gld_lds(src, dst);
        }
    }
    __syncthreads();

    // ---- accumulators init with bias (C/D col = co) ----
    f32x16 acc[2][2];
    {
        const float bv0 = b2[c];
        const float bv1 = b2[32 + c];
#pragma unroll
        for (int i = 0; i < 16; ++i) {
            acc[0][0][i] = bv0; acc[1][0][i] = bv0;
            acc[0][1][i] = bv1; acc[1][1][i] = bv1;
        }
    }

    // per-lane A addressing: row = (zw+kd)*6 + mh*2 + yl + khp
    const unsigned char* aRow =
        smem + (size_t)(mh * 2 + yl) * LDS_STRIDE + (size_t)zw * (6 * LDS_STRIDE);
    int xoff[2][3], swx[2][3];
#pragma unroll
    for (int mt = 0; mt < 2; ++mt)
#pragma unroll
        for (int kw = 0; kw < 3; ++kw) {
            const int xin = mt * 12 + xi + kw;
            xoff[mt][kw] = xin * 64;
            swx[mt][kw]  = (xin >> 1) & 3;
        }
    const int kc0 = kh, kc1 = 2 + kh;

    u32x4 Bs[2][4];
#define B_LOAD(slot, t)                                                        \
    { const char* p_ = wBl + (size_t)(t) * 4096;                               \
      asm volatile("global_load_dwordx4 %0, %4, off\n\t"                       \
                   "global_load_dwordx4 %1, %4, off offset:1024\n\t"           \
                   "global_load_dwordx4 %2, %4, off offset:2048\n\t"           \
                   "global_load_dwordx4 %3, %4, off offset:3072"               \
                   : "=&v"(Bs[slot][0]), "=&v"(Bs[slot][1]),                   \
                     "=&v"(Bs[slot][2]), "=&v"(Bs[slot][3])                    \
                   : "v"(p_)); }

    // tap-0 B load (staging drained by barrier -> vmcnt counts exact)
    B_LOAD(0, 0)

    // ---- barrier-free K-loop over 27 taps, fully unrolled ----
#pragma unroll
    for (int tap = 0; tap < 27; ++tap) {
        const int cur = tap & 1;

        if (tap < 26) B_LOAD(cur ^ 1, tap + 1)

        if (tap < 26) asm volatile("s_waitcnt vmcnt(4)");
        else          asm volatile("s_waitcnt vmcnt(0)");

        asm volatile("" : "+v"(Bs[cur][0]), "+v"(Bs[cur][1]),
                          "+v"(Bs[cur][2]), "+v"(Bs[cur][3]));
        const bf16x8 B00 = __builtin_bit_cast(bf16x8, Bs[cur][0]); // ks0,nf0
        const bf16x8 B01 = __builtin_bit_cast(bf16x8, Bs[cur][1]); // ks0,nf1
        const bf16x8 B10 = __builtin_bit_cast(bf16x8, Bs[cur][2]); // ks1,nf0
        const bf16x8 B11 = __builtin_bit_cast(bf16x8, Bs[cur][3]); // ks1,nf1

        const int kd  = tap / 9;
        const int khp = (tap - kd * 9) / 3;
        const int kw  = tap - kd * 9 - khp * 3;
        const unsigned char* rp = aRow + (kd * 6 + khp) * LDS_STRIDE;

#pragma unroll
        for (int mt = 0; mt < 2; ++mt) {
            const int xo = xoff[mt][kw];
            const int sw = swx[mt][kw];
            const bf16x8 a0 = *reinterpret_cast<const bf16x8*>(
                rp + xo + ((kc0 ^ sw) << 4));
            const bf16x8 a1 = *reinterpret_cast<const bf16x8*>(
                rp + xo + ((kc1 ^ sw) << 4));
            acc[mt][0] = __builtin_amdgcn_mfma_f32_32x32x16_bf16(a0, B00, acc[mt][0], 0, 0, 0);
            acc[mt][1] = __builtin_amdgcn_mfma_f32_32x32x16_bf16(a0, B01, acc[mt][1], 0, 0, 0);
            acc[mt][0] = __builtin_amdgcn_mfma_f32_32x32x16_bf16(a1, B10, acc[mt][0], 0, 0, 0);
            acc[mt][1] = __builtin_amdgcn_mfma_f32_32x32x16_bf16(a1, B11, acc[mt][1], 0, 0, 0);
        }
    }
#undef B_LOAD

    // ---- epilogue: C/D row m = (reg&3)+8*(reg>>2)+4*kh; col = co ----
    // site: yy = m>>4, x = x0 + (m&15); reg-quad qd -> float4 at
    // x = x0 + (qd&1)*8 + 4*kh, y = ybase + (qd>>1). Overlap x12-15 writes
    // identical values twice (same inputs, same op order) — benign.
    const int z = z0 + zw;
    const int ybase = y0 + mh * 2;
#pragma unroll
    for (int mt = 0; mt < 2; ++mt) {
        const int x0 = mt * 12;
#pragma unroll
        for (int nf = 0; nf < 2; ++nf) {
            const int co = nf * 32 + c;
            float* ob = out + ((size_t)b * 64 + co) * OUT_CSTR
                            + (size_t)z * 784 + (size_t)ybase * 28 + x0;
#pragma unroll
            for (int qd = 0; qd < 4; ++qd) {
                const int yy = qd >> 1;
                const int xo = (qd & 1) * 8 + 4 * kh;
                float4 st;
                st.x = fmaxf(acc[mt][nf][qd * 4 + 0], 0.f);
                st.y = fmaxf(acc[mt][nf][qd * 4 + 1], 0.f);
                st.z = fmaxf(acc[mt][nf][qd * 4 + 2], 0.f);
                st.w = fmaxf(acc[mt][nf][qd * 4 + 3], 0.f);
                *reinterpret_cast<float4*>(ob + yy * 28 + xo) = st;
            }
        }
    }
}

extern "C" void kernel_launch(void* const* d_in, const int* in_sizes, int n_in,
                              void* d_out, int out_size, void* d_ws, size_t ws_size,
                              hipStream_t stream)
{
    const float* x  = (const float*)d_in[0];
    const float* w1 = (const float*)d_in[1];
    const float* b1 = (const float*)d_in[2];
    const float* w2 = (const float*)d_in[3];
    const float* b2 = (const float*)d_in[4];
    float* out = (float*)d_out;

    u16* wB = (u16*)d_ws;                               // 110,592 B packed weights
    u16* h1 = (u16*)((char*)d_ws + 131072);

    pack_w2<<<27, 256, 0, stream>>>(w2, wB);

    const size_t per_batch = (size_t)H1_BATCH * 2;      // 1,728,000 B
    size_t avail = ws_size > 131072 ? ws_size - 131072 : 0;
    int bchunk = (int)(avail / per_batch);
    if (bchunk < 1)  bchunk = 1;
    if (bchunk > 64) bchunk = 64;

    for (int b0 = 0; b0 < 64; b0 += bchunk) {
        int bc = 64 - b0;
        if (bc > bchunk) bc = bchunk;
        conv1_relu<<<dim3(30, 5, bc), 256, 0, stream>>>(x, w1, b1, h1, b0);
        conv2_mfma<<<dim3(49 * bc), 512, 0, stream>>>(h1, wB, b2, out, b0);
    }
}

// Round 20
// 255.437 us; speedup vs baseline: 1.0926x; 1.0926x over previous
//
#include <hip/hip_runtime.h>
#include <cstdint>
#include <cstddef>

typedef __attribute__((ext_vector_type(8))) short bf16x8;
typedef __attribute__((ext_vector_type(4))) float f32x4;
typedef __attribute__((ext_vector_type(4))) unsigned int u32x4;
typedef unsigned short u16;

#define H1_ROW_B   1920                 /* packed row: 30x * 32ci * 2B     */
#define H1_BATCH   (30 * 30 * 960)      /* elems per batch (864000)        */
#define LDS_STRIDE 1952                 /* 1920 + 32: 488 dw = 8-bank row shift */
#define OUT_CSTR   21952                /* 28*28*28                        */

__device__ __forceinline__ u16 f2bf(float f) {
    union { float f; unsigned u; } v; v.f = f;
    unsigned r = v.u + 0x7FFF + ((v.u >> 16) & 1);   // RNE
    return (u16)(r >> 16);
}

__device__ __forceinline__ void fma4(float4& a, float s, const float4& w) {
    a.x = fmaf(s, w.x, a.x);
    a.y = fmaf(s, w.y, a.y);
    a.z = fmaf(s, w.z, a.z);
    a.w = fmaf(s, w.w, a.w);
}

__device__ __forceinline__ void gld_lds(const char* src, unsigned char* dst) {
    __builtin_amdgcn_global_load_lds(
        (const __attribute__((address_space(1))) void*)src,
        (__attribute__((address_space(3))) void*)dst, 16, 0, 0);
}

// ---------------- conv1 + bias + relu -> bf16 h1 [bl][z][y][30x][32ci] ----
// x staged in LDS (one coalesced pass); weights in registers (L1-broadcast).
__global__ __launch_bounds__(256) void conv1_relu(
    const float* __restrict__ x, const float* __restrict__ w1,
    const float* __restrict__ b1, u16* __restrict__ h1, int b0)
{
    __shared__ float xs[3 * 8 * 32];     // [zp][y][x] f32, 3 KB

    const int z   = blockIdx.x;        // 0..29
    const int yt  = blockIdx.y;        // 0..4
    const int bl  = blockIdx.z;
    const int b   = b0 + bl;
    const int tid = threadIdx.x;
    const int y0  = yt * 6;

    // stage x[z..z+2][y0..y0+7][0..31] (768 f32) : 192 threads x float4
    if (tid < 192) {
        const int idx = tid * 4;         // 0..764
        const int zp  = idx >> 8;
        const int rem = idx & 255;
        const int yy  = rem >> 5;
        const int xx  = rem & 31;
        const float4 v = *reinterpret_cast<const float4*>(
            x + (size_t)b * 32768 + ((size_t)(z + zp) * 32 + (y0 + yy)) * 32 + xx);
        *reinterpret_cast<float4*>(&xs[idx]) = v;
    }

    const int c4   = tid & 7;          // ci c4*4 .. +3
    const int slot = tid >> 3;         // 0..31; active slots 0..29

    // weights -> registers (L1-broadcast: all waves read the same 3.5 KB)
    float4 wr[27];
#pragma unroll
    for (int t = 0; t < 27; ++t)
        wr[t] = *reinterpret_cast<const float4*>(w1 + t * 32 + c4 * 4);
    const float4 bias = *reinterpret_cast<const float4*>(b1 + c4 * 4);

    __syncthreads();

    u16* h1b = h1 + (size_t)bl * H1_BATCH;

    if (slot < 30) {
#pragma unroll
        for (int j = 0; j < 3; ++j) {
            const int p  = slot + 30 * j;     // 0..89 pair index
            const int yy = p / 15;
            const int xx = (p - yy * 15) * 2; // 0,2,..,28 (8B aligned)
            const int y  = y0 + yy;

            float4 acc0 = bias, acc1 = bias;
#pragma unroll
            for (int kd = 0; kd < 3; ++kd) {
#pragma unroll
                for (int kh = 0; kh < 3; ++kh) {
                    const float* row = &xs[((kd * 8) + (yy + kh)) * 32 + xx];
                    const float2 v01 = *reinterpret_cast<const float2*>(row);
                    const float2 v23 = *reinterpret_cast<const float2*>(row + 2);
                    const int t = (kd * 3 + kh) * 3;
                    fma4(acc0, v01.x, wr[t + 0]);
                    fma4(acc0, v01.y, wr[t + 1]);
                    fma4(acc0, v23.x, wr[t + 2]);
                    fma4(acc1, v01.y, wr[t + 0]);
                    fma4(acc1, v23.x, wr[t + 1]);
                    fma4(acc1, v23.y, wr[t + 2]);
                }
            }
            ushort4 s0, s1;
            s0.x = f2bf(fmaxf(acc0.x, 0.f)); s0.y = f2bf(fmaxf(acc0.y, 0.f));
            s0.z = f2bf(fmaxf(acc0.z, 0.f)); s0.w = f2bf(fmaxf(acc0.w, 0.f));
            s1.x = f2bf(fmaxf(acc1.x, 0.f)); s1.y = f2bf(fmaxf(acc1.y, 0.f));
            s1.z = f2bf(fmaxf(acc1.z, 0.f)); s1.w = f2bf(fmaxf(acc1.w, 0.f));
            u16* dst = h1b + ((size_t)(z * 30 + y) * 30 + xx) * 32 + c4 * 4;
            *reinterpret_cast<ushort4*>(dst)      = s0;
            *reinterpret_cast<ushort4*>(dst + 32) = s1;
        }
    }
}

// ---------------- pack w2 fp32 DHWIO -> bf16 B-fragments ------------------
// wB[((tap*4 + nt)*64 + lane)*8 + j] = bf16(w2[tap][(lane>>4)*8 + j][nt*16 + (lane&15)])
__global__ __launch_bounds__(256) void pack_w2(
    const float* __restrict__ w2, u16* __restrict__ wB)
{
    const int tap = blockIdx.x;      // 0..26
    const int tid = threadIdx.x;
    const int nt = tid >> 6;
    const int l  = tid & 63;
    const int r = l & 15, q = l >> 4;
    u16* dst = wB + ((size_t)(tap * 4 + nt) * 64 + l) * 8;
#pragma unroll
    for (int j = 0; j < 8; ++j)
        dst[j] = f2bf(w2[(size_t)(tap * 32 + q * 8 + j) * 64 + nt * 16 + r]);
}

// ---------------- conv2 implicit-GEMM MFMA, 8-wave N-split ----------------
// Best measured config (r9/r14/r18): Grid 49*bc x 512 thr (XCD-swizzled).
// Block: 4z x 4y x 28x. 8 waves: wave wv -> z-plane zw=wv>>1, N-half nh.
// Per wave: 7 m-tiles x 2 n-frags (16x16x32). A in LDS (36 x 1920 B,
// stride 1952, 0-conflict). B global 2 KB/wave/tap, 2-deep, counted vmcnt.
// No setprio. 2 blocks/CU, 16 waves/CU. Epilogue nt-outer (112 B runs).
__global__ __launch_bounds__(512, 4) void conv2_mfma(
    const u16* __restrict__ h1, const u16* __restrict__ wB,
    const float* __restrict__ b2, float* __restrict__ out, int b0)
{
    __shared__ __align__(16) unsigned char smem[36 * LDS_STRIDE];  // 70272 B

    const int g   = gridDim.x;
    const int bid = blockIdx.x;
    const int lb  = (g % 8 == 0) ? ((bid & 7) * (g >> 3) + (bid >> 3)) : bid;

    const int t0  = lb % 49;
    const int bl  = lb / 49;
    const int yg  = t0 % 7;
    const int zt  = t0 / 7;

    const int b  = b0 + bl;
    const int y0 = yg * 4, z0 = zt * 4;
    const int tid = threadIdx.x;
    const int wv  = tid >> 6;       // 0..7
    const int l   = tid & 63;
    const int zw  = wv >> 1;        // wave z offset 0..3
    const int nh  = wv & 1;         // wave N half
    const int r = l & 15, q = l >> 4;
    const int yl = r >> 2, xg = r & 3;

    const char* wBl = (const char*)wB + nh * 2048 + l * 16;

    // ---- stage A: 36 rows x 1920 B, chunks at 0 and 896 (128 B overlap) --
    {
        const char* gbase = (const char*)(h1 + (size_t)bl * H1_BATCH);
        for (int c = wv; c < 72; c += 8) {           // wave-uniform chunks
            const int rid = c >> 1, half = c & 1;
            const int zz = rid / 6, yy = rid - zz * 6;
            const char* src = gbase
                + (size_t)((z0 + zz) * 30 + (y0 + yy)) * H1_ROW_B
                + half * 896 + l * 16;
            unsigned char* dst = smem + rid * LDS_STRIDE + half * 896 + l * 16;
            gld_lds(src, dst);
        }
    }
    __syncthreads();   // drains staging (vmcnt(0)) + publishes LDS

    // ---- accumulators init with bias (co = nh*32 + nt*16 + r) ----
    f32x4 acc[7][2];
    {
        const float bv0 = b2[nh * 32 + r];
        const float bv1 = b2[nh * 32 + 16 + r];
#pragma unroll
        for (int mt = 0; mt < 7; ++mt) {
            acc[mt][0] = (f32x4){bv0, bv0, bv0, bv0};
            acc[mt][1] = (f32x4){bv1, bv1, bv1, bv1};
        }
    }

    // per-lane A base: row (zw+kd)*6 + (yl+kh), x = mt*4 + xg + kw, K-qtr q
    const unsigned char* aBase =
        smem + (zw * 6 + yl) * LDS_STRIDE + xg * 64 + q * 16;

    u32x4 Bs[3][2];
#define B_LOAD(slot, t)                                                        \
    { const char* p_ = wBl + (size_t)(t) * 4096;                               \
      asm volatile("global_load_dwordx4 %0, %2, off\n\t"                       \
                   "global_load_dwordx4 %1, %2, off offset:1024"               \
                   : "=&v"(Bs[slot][0]), "=&v"(Bs[slot][1]) : "v"(p_)); }

    // 2-deep prologue (staging already drained -> vmcnt counting exact)
    B_LOAD(0, 0)
    B_LOAD(1, 1)

    // ---- barrier-free K-loop over 27 taps, fully unrolled ----
#pragma unroll
    for (int tap = 0; tap < 27; ++tap) {
        const int cur = tap % 3;

        if (tap < 25) B_LOAD((tap + 2) % 3, tap + 2)

        // after wait: taps t+1 (and t+2 if issued) remain in flight
        if (tap < 25)       asm volatile("s_waitcnt vmcnt(4)");
        else if (tap == 25) asm volatile("s_waitcnt vmcnt(2)");
        else                asm volatile("s_waitcnt vmcnt(0)");

        asm volatile("" : "+v"(Bs[cur][0]), "+v"(Bs[cur][1]));
        const bf16x8 B0 = __builtin_bit_cast(bf16x8, Bs[cur][0]);
        const bf16x8 B1 = __builtin_bit_cast(bf16x8, Bs[cur][1]);

        const int kd = tap / 9;
        const int kh = (tap - kd * 9) / 3;
        const int kw = tap - kd * 9 - kh * 3;
        const unsigned char* ap = aBase + (kd * 6 + kh) * LDS_STRIDE + kw * 64;

#pragma unroll
        for (int mt = 0; mt < 7; ++mt) {
            const bf16x8 a = *reinterpret_cast<const bf16x8*>(ap + mt * 256);
            acc[mt][0] = __builtin_amdgcn_mfma_f32_16x16x32_bf16(a, B0, acc[mt][0], 0, 0, 0);
            acc[mt][1] = __builtin_amdgcn_mfma_f32_16x16x32_bf16(a, B1, acc[mt][1], 0, 0, 0);
        }
    }
#undef B_LOAD

    // ---- epilogue (nt OUTER, mt INNER): lane (r,q): co = nh*32+nt*16+r,
    // y = y0+q, x = mt*4..+3 — 7 consecutive 16B stores per lane = 112 B run
    const int z = z0 + zw;
    float* ob = out + ((size_t)b * 64 + nh * 32 + r) * OUT_CSTR
                    + (size_t)z * 784 + (size_t)(y0 + q) * 28;
#pragma unroll
    for (int nt = 0; nt < 2; ++nt) {
        float* obn = ob + (size_t)nt * 16 * OUT_CSTR;
#pragma unroll
        for (int mt = 0; mt < 7; ++mt) {
            const f32x4 v = acc[mt][nt];
            float4 st;
            st.x = fmaxf(v.x, 0.f);
            st.y = fmaxf(v.y, 0.f);
            st.z = fmaxf(v.z, 0.f);
            st.w = fmaxf(v.w, 0.f);
            *reinterpret_cast<float4*>(obn + mt * 4) = st;
        }
    }
}

extern "C" void kernel_launch(void* const* d_in, const int* in_sizes, int n_in,
                              void* d_out, int out_size, void* d_ws, size_t ws_size,
                              hipStream_t stream)
{
    const float* x  = (const float*)d_in[0];
    const float* w1 = (const float*)d_in[1];
    const float* b1 = (const float*)d_in[2];
    const float* w2 = (const float*)d_in[3];
    const float* b2 = (const float*)d_in[4];
    float* out = (float*)d_out;

    u16* wB = (u16*)d_ws;                               // 110,592 B packed weights
    u16* h1 = (u16*)((char*)d_ws + 131072);

    pack_w2<<<27, 256, 0, stream>>>(w2, wB);

    const size_t per_batch = (size_t)H1_BATCH * 2;      // 1,728,000 B
    size_t avail = ws_size > 131072 ? ws_size - 131072 : 0;
    int bchunk = (int)(avail / per_batch);
    if (bchunk < 1)  bchunk = 1;
    if (bchunk > 64) bchunk = 64;

    for (int b0 = 0; b0 < 64; b0 += bchunk) {
        int bc = 64 - b0;
        if (bc > bchunk) bc = bchunk;
        conv1_relu<<<dim3(30, 5, bc), 256, 0, stream>>>(x, w1, b1, h1, b0);
        conv2_mfma<<<dim3(49 * bc), 512, 0, stream>>>(h1, wB, b2, out, b0);
    }
}